// Round 1
// baseline (15067.612 us; speedup 1.0000x reference)
//
#include <hip/hip_runtime.h>
#include <math.h>

// Problem geometry (fixed by the reference):
//   preds   : (2, 2, 128, 128, 128) float32
//   targets : (2, 1, 128, 128, 128) int32
//   output  : scalar float32 = mean over (2,128,128,128) of
//             0.5*ce*(1 + 0.5*m_neg + 0.5*m_pos)
#define VOL   (128 * 128 * 128)   // 2,097,152 voxels per volume
#define NB    2                   // batch
#define TOTAL (NB * VOL)          // 4,194,304

#define INVP   0x7FFFFFFFu        // background sentinel in parent arrays
#define FLAGB  0x80000000u        // "component has an error voxel" bit (on root entry)
#define IDXM   0x7FFFFFFFu        // mask off the flag bit

// ---------------- union-find primitives ----------------
// Invariant: parent values only ever DECREASE (atomicMin everywhere), and
// parent[i] <= i for fg voxels. Final root of each component = min voxel id.
// Deterministic regardless of thread interleaving.

__device__ __forceinline__ unsigned find_root(unsigned* P, unsigned i) {
    // path-halving find; compression stores use atomicMin (never raises a
    // pointer, so concurrent lost-update cannot un-merge components)
    while (true) {
        unsigned p = P[i] & IDXM;
        if (p == i) return i;
        unsigned gp = P[p] & IDXM;
        if (gp != p) atomicMin(&P[i], gp);
        i = gp;
    }
}

__device__ __forceinline__ void unite(unsigned* P, unsigned a, unsigned b) {
    a = find_root(P, a);
    b = find_root(P, b);
    while (a != b) {
        if (b > a) { unsigned t = a; a = b; b = t; }   // a > b: link a under b
        unsigned old = atomicMin(&P[a], b);
        if (old == a) return;                          // we linked root a -> b
        a = find_root(P, old & IDXM);                  // raced: follow old link
        b = find_root(P, b);
    }
}

// ---------------- kernels ----------------

__global__ void k_init(const float* __restrict__ preds,
                       const int* __restrict__ tgt,
                       unsigned* __restrict__ Pp,
                       unsigned* __restrict__ Pt) {
    unsigned g = blockIdx.x * blockDim.x + threadIdx.x;
    if (g >= TOTAL) return;
    unsigned b = g >> 21;               // /VOL
    unsigned i = g & (VOL - 1);
    float p1 = preds[((size_t)(b * 2 + 1)) * VOL + i];  // channel 1 logit
    int   t  = tgt[g];
    Pp[g] = (p1 > 0.0f) ? g : INVP;     // pred_fg
    Pt[g] = (t > 0)     ? g : INVP;     // tgt_fg
}

__global__ void k_merge(unsigned* __restrict__ Pp, unsigned* __restrict__ Pt) {
    unsigned g = blockIdx.x * blockDim.x + threadIdx.x;
    if (g >= TOTAL) return;
    unsigned x = g & 127;
    unsigned y = (g >> 7) & 127;
    unsigned z = (g >> 14) & 127;       // z<127 also keeps us inside the batch
    if (Pp[g] != INVP) {
        if (x < 127 && Pp[g + 1]     != INVP) unite(Pp, g, g + 1);
        if (y < 127 && Pp[g + 128]   != INVP) unite(Pp, g, g + 128);
        if (z < 127 && Pp[g + 16384] != INVP) unite(Pp, g, g + 16384);
    }
    if (Pt[g] != INVP) {
        if (x < 127 && Pt[g + 1]     != INVP) unite(Pt, g, g + 1);
        if (y < 127 && Pt[g + 128]   != INVP) unite(Pt, g, g + 128);
        if (z < 127 && Pt[g + 16384] != INVP) unite(Pt, g, g + 16384);
    }
}

// Compress every fg voxel to point directly at its root, and set the FLAG bit
// on the root when the voxel is an error w.r.t. the other segmentation.
// Flag bits live only on ROOT entries; compression stores only touch
// non-root entries (r != g guard), so the two never clobber each other.
__global__ void k_flag(unsigned* __restrict__ Pp, unsigned* __restrict__ Pt) {
    unsigned g = blockIdx.x * blockDim.x + threadIdx.x;
    if (g >= TOTAL) return;
    unsigned vp = Pp[g], vt = Pt[g];
    bool pf = (vp != INVP), tf = (vt != INVP);
    if (pf) {
        unsigned r = find_root(Pp, g);
        if (r != g) atomicMin(&Pp[g], r);          // direct link for final pass
        if (!tf) atomicOr(&Pp[r], FLAGB);          // m_pos: pred comp not covered by tgt
    }
    if (tf) {
        unsigned r = find_root(Pt, g);
        if (r != g) atomicMin(&Pt[g], r);
        if (!pf) atomicOr(&Pt[r], FLAGB);          // m_neg: tgt comp not covered by pred
    }
}

__global__ void k_loss(const float* __restrict__ preds,
                       const int* __restrict__ tgt,
                       const unsigned* __restrict__ Pp,
                       const unsigned* __restrict__ Pt,
                       float* __restrict__ partial) {
    float acc = 0.0f;
    for (unsigned g = blockIdx.x * blockDim.x + threadIdx.x; g < TOTAL;
         g += gridDim.x * blockDim.x) {
        unsigned b = g >> 21;
        unsigned i = g & (VOL - 1);
        float p0 = preds[((size_t)(b * 2 + 0)) * VOL + i];
        float p1 = preds[((size_t)(b * 2 + 1)) * VOL + i];
        int   t  = tgt[g];
        // 2-class CE: -log_softmax(preds)[t] == softplus(p_other - p_t)
        float z  = (t > 0) ? (p0 - p1) : (p1 - p0);
        float ce = (z > 0.0f) ? (z + log1pf(expf(-z))) : log1pf(expf(z));

        unsigned vp = Pp[g], vt = Pt[g];
        float crit = 0.0f;
        if (vt != INVP) {                        // voxel in a tgt component
            unsigned r = vt & IDXM;
            if (Pt[r] & FLAGB) crit += 0.5f;     // BETA * m_neg
        }
        if (vp != INVP) {                        // voxel in a pred component
            unsigned r = vp & IDXM;
            if (Pp[r] & FLAGB) crit += 0.5f;     // (1-BETA) * m_pos
        }
        // (1-ALPHA)*ce + ALPHA*crit*ce  with ALPHA=0.5
        acc += 0.5f * ce * (1.0f + crit);
    }
    // block reduction (wave64)
    for (int off = 32; off > 0; off >>= 1) acc += __shfl_down(acc, off);
    __shared__ float s[4];                       // 256 threads / 64
    int wid = threadIdx.x >> 6, lane = threadIdx.x & 63;
    if (lane == 0) s[wid] = acc;
    __syncthreads();
    if (threadIdx.x == 0) {
        float tacc = 0.0f;
        for (int w = 0; w < (int)(blockDim.x >> 6); ++w) tacc += s[w];
        partial[blockIdx.x] = tacc;
    }
}

__global__ void k_final(const float* __restrict__ partial, int n,
                        float* __restrict__ out) {
    double acc = 0.0;
    for (int i = threadIdx.x; i < n; i += blockDim.x) acc += (double)partial[i];
    for (int off = 32; off > 0; off >>= 1) acc += __shfl_down(acc, off);
    __shared__ double s[4];
    int wid = threadIdx.x >> 6, lane = threadIdx.x & 63;
    if (lane == 0) s[wid] = acc;
    __syncthreads();
    if (threadIdx.x == 0) {
        double t = 0.0;
        for (int w = 0; w < (int)(blockDim.x >> 6); ++w) t += s[w];
        out[0] = (float)(t / (double)TOTAL);
    }
}

// ---------------- launch ----------------

extern "C" void kernel_launch(void* const* d_in, const int* in_sizes, int n_in,
                              void* d_out, int out_size, void* d_ws, size_t ws_size,
                              hipStream_t stream) {
    const float* preds   = (const float*)d_in[0];   // (2,2,128,128,128) f32
    const int*   targets = (const int*)d_in[1];     // (2,1,128,128,128) i32
    float*       out     = (float*)d_out;           // scalar

    // workspace layout: Pp[TOTAL] u32 | Pt[TOTAL] u32 | partial[2048] f32
    unsigned* Pp = (unsigned*)d_ws;
    unsigned* Pt = Pp + TOTAL;
    float* partial = (float*)(Pt + TOTAL);

    const int T = 256;
    const int B = TOTAL / T;            // 16384 blocks, exact
    k_init <<<B, T, 0, stream>>>(preds, targets, Pp, Pt);
    k_merge<<<B, T, 0, stream>>>(Pp, Pt);
    k_flag <<<B, T, 0, stream>>>(Pp, Pt);

    const int RB = 2048;                // grid-stride reduction
    k_loss <<<RB, T, 0, stream>>>(preds, targets, Pp, Pt, partial);
    k_final<<<1, T, 0, stream>>>(partial, RB, out);
}

// Round 5
// 869.083 us; speedup vs baseline: 17.3374x; 17.3374x over previous
//
#include <hip/hip_runtime.h>
#include <math.h>

// Problem geometry (fixed by the reference):
//   preds   : (2, 2, 128, 128, 128) float32
//   targets : (2, 1, 128, 128, 128) int32
//   output  : scalar float32 = mean over (2,128,128,128) of
//             0.5*ce*(1 + 0.5*m_neg + 0.5*m_pos)
#define VOL   (128 * 128 * 128)   // 2,097,152 voxels per volume
#define NB    2                   // batch
#define TOTAL (NB * VOL)          // 4,194,304

#define INVP   0x7FFFFFFFu        // background sentinel in parent arrays
#define FLAGB  0x80000000u        // "component has an error voxel" bit (on root entry)
#define IDXM   0x7FFFFFFFu        // mask off the flag bit

// ---------------- union-find primitives ----------------
// Invariant: parent values only ever DECREASE (atomicMin everywhere), and
// parent[i] <= i for fg voxels. Final root of each component = min voxel id.
// Deterministic regardless of thread interleaving.

__device__ __forceinline__ unsigned find_root(unsigned* P, unsigned i) {
    // path-halving find; compression stores use atomicMin (never raises a
    // pointer, so concurrent lost-update cannot un-merge components).
    // Root entries may carry FLAGB; IDXM strips it. Halving never writes a
    // root entry (gp==p there), so flags are never clobbered here.
    while (true) {
        unsigned p = P[i] & IDXM;
        if (p == i) return i;
        unsigned gp = P[p] & IDXM;
        if (gp != p) atomicMin(&P[i], gp);
        i = gp;
    }
}

__device__ __forceinline__ void unite(unsigned* P, unsigned a, unsigned b) {
    a = find_root(P, a);
    b = find_root(P, b);
    while (a != b) {
        if (b > a) { unsigned t = a; a = b; b = t; }   // a > b: link a under b
        unsigned old = atomicMin(&P[a], b);
        if (old == a) return;                          // we linked root a -> b
        a = find_root(P, old & IDXM);                  // raced: follow old link
        b = find_root(P, b);
    }
}

// Flag the root of g's component, with wave-level dedup + test-before-set to
// avoid the same-address atomic storm (the giant percolation component makes
// ~1e6 voxels share ONE root: naive atomicOr serializes at ~7 ns each = 14 ms,
// measured in R1). `need` lanes must be in convergent control flow.
__device__ __forceinline__ void flag_root_dedup(unsigned* P, bool need, unsigned r) {
    int lane = threadIdx.x & 63;
    unsigned long long rem = __ballot(need);
    while (rem) {
        int src = __ffsll(rem) - 1;
        unsigned rr = __shfl(r, src);
        if (need && r == rr) {
            if (lane == src) {
                // test-before-set: flags are monotonic (never cleared), so a
                // visible 1 is always genuine; a stale 0 just costs one atomic.
                if (!(P[rr] & FLAGB)) atomicOr(&P[rr], FLAGB);
            }
            need = false;
        }
        rem = __ballot(need);
    }
}

// ---------------- kernels ----------------

__global__ void k_init(const float* __restrict__ preds,
                       const int* __restrict__ tgt,
                       unsigned* __restrict__ Pp,
                       unsigned* __restrict__ Pt) {
    unsigned g = blockIdx.x * blockDim.x + threadIdx.x;
    if (g >= TOTAL) return;
    unsigned b = g >> 21;               // /VOL
    unsigned i = g & (VOL - 1);
    float p1 = preds[((size_t)(b * 2 + 1)) * VOL + i];  // channel 1 logit
    int   t  = tgt[g];
    Pp[g] = (p1 > 0.0f) ? g : INVP;     // pred_fg
    Pt[g] = (t > 0)     ? g : INVP;     // tgt_fg
}

__global__ void k_merge(unsigned* __restrict__ Pp, unsigned* __restrict__ Pt) {
    unsigned g = blockIdx.x * blockDim.x + threadIdx.x;
    if (g >= TOTAL) return;
    unsigned x = g & 127;
    unsigned y = (g >> 7) & 127;
    unsigned z = (g >> 14) & 127;       // z<127 also keeps us inside the batch
    if (Pp[g] != INVP) {
        if (x < 127 && Pp[g + 1]     != INVP) unite(Pp, g, g + 1);
        if (y < 127 && Pp[g + 128]   != INVP) unite(Pp, g, g + 128);
        if (z < 127 && Pp[g + 16384] != INVP) unite(Pp, g, g + 16384);
    }
    if (Pt[g] != INVP) {
        if (x < 127 && Pt[g + 1]     != INVP) unite(Pt, g, g + 1);
        if (y < 127 && Pt[g + 128]   != INVP) unite(Pt, g, g + 128);
        if (z < 127 && Pt[g + 16384] != INVP) unite(Pt, g, g + 16384);
    }
}

// Compress every fg voxel to point directly at its root, and set the FLAG bit
// on the root when the voxel is an error w.r.t. the other segmentation.
// Flag bits live only on ROOT entries; compression atomics only touch
// non-root entries (r != g guard), so the two never clobber each other.
__global__ void k_flag(unsigned* __restrict__ Pp, unsigned* __restrict__ Pt) {
    unsigned g = blockIdx.x * blockDim.x + threadIdx.x;
    if (g >= TOTAL) return;
    unsigned vp = Pp[g], vt = Pt[g];
    bool pf = (vp != INVP), tf = (vt != INVP);

    unsigned rp = 0, rt = 0;
    if (pf) {
        rp = find_root(Pp, g);
        if (rp != g) atomicMin(&Pp[g], rp);        // direct link for final pass
    }
    if (tf) {
        rt = find_root(Pt, g);
        if (rt != g) atomicMin(&Pt[g], rt);
    }
    // m_pos: pred component contains a voxel outside tgt_fg
    flag_root_dedup(Pp, pf && !tf, rp);
    // m_neg: tgt component contains a voxel outside pred_fg
    flag_root_dedup(Pt, tf && !pf, rt);
}

__global__ void k_loss(const float* __restrict__ preds,
                       const int* __restrict__ tgt,
                       const unsigned* __restrict__ Pp,
                       const unsigned* __restrict__ Pt,
                       float* __restrict__ partial) {
    float acc = 0.0f;
    for (unsigned g = blockIdx.x * blockDim.x + threadIdx.x; g < TOTAL;
         g += gridDim.x * blockDim.x) {
        unsigned b = g >> 21;
        unsigned i = g & (VOL - 1);
        float p0 = preds[((size_t)(b * 2 + 0)) * VOL + i];
        float p1 = preds[((size_t)(b * 2 + 1)) * VOL + i];
        int   t  = tgt[g];
        // 2-class CE: -log_softmax(preds)[t] == softplus(p_other - p_t)
        float z  = (t > 0) ? (p0 - p1) : (p1 - p0);
        float ce = (z > 0.0f) ? (z + log1pf(expf(-z))) : log1pf(expf(z));

        unsigned vp = Pp[g], vt = Pt[g];
        float crit = 0.0f;
        if (vt != INVP) {                        // voxel in a tgt component
            unsigned r = vt & IDXM;
            if (Pt[r] & FLAGB) crit += 0.5f;     // BETA * m_neg
        }
        if (vp != INVP) {                        // voxel in a pred component
            unsigned r = vp & IDXM;
            if (Pp[r] & FLAGB) crit += 0.5f;     // (1-BETA) * m_pos
        }
        // (1-ALPHA)*ce + ALPHA*crit*ce  with ALPHA=0.5
        acc += 0.5f * ce * (1.0f + crit);
    }
    // block reduction (wave64)
    for (int off = 32; off > 0; off >>= 1) acc += __shfl_down(acc, off);
    __shared__ float s[4];                       // 256 threads / 64
    int wid = threadIdx.x >> 6, lane = threadIdx.x & 63;
    if (lane == 0) s[wid] = acc;
    __syncthreads();
    if (threadIdx.x == 0) {
        float tacc = 0.0f;
        for (int w = 0; w < (int)(blockDim.x >> 6); ++w) tacc += s[w];
        partial[blockIdx.x] = tacc;
    }
}

__global__ void k_final(const float* __restrict__ partial, int n,
                        float* __restrict__ out) {
    double acc = 0.0;
    for (int i = threadIdx.x; i < n; i += blockDim.x) acc += (double)partial[i];
    for (int off = 32; off > 0; off >>= 1) acc += __shfl_down(acc, off);
    __shared__ double s[4];
    int wid = threadIdx.x >> 6, lane = threadIdx.x & 63;
    if (lane == 0) s[wid] = acc;
    __syncthreads();
    if (threadIdx.x == 0) {
        double t = 0.0;
        for (int w = 0; w < (int)(blockDim.x >> 6); ++w) t += s[w];
        out[0] = (float)(t / (double)TOTAL);
    }
}

// ---------------- launch ----------------

extern "C" void kernel_launch(void* const* d_in, const int* in_sizes, int n_in,
                              void* d_out, int out_size, void* d_ws, size_t ws_size,
                              hipStream_t stream) {
    const float* preds   = (const float*)d_in[0];   // (2,2,128,128,128) f32
    const int*   targets = (const int*)d_in[1];     // (2,1,128,128,128) i32
    float*       out     = (float*)d_out;           // scalar

    // workspace layout: Pp[TOTAL] u32 | Pt[TOTAL] u32 | partial[2048] f32
    unsigned* Pp = (unsigned*)d_ws;
    unsigned* Pt = Pp + TOTAL;
    float* partial = (float*)(Pt + TOTAL);

    const int T = 256;
    const int B = TOTAL / T;            // 16384 blocks, exact
    k_init <<<B, T, 0, stream>>>(preds, targets, Pp, Pt);
    k_merge<<<B, T, 0, stream>>>(Pp, Pt);
    k_flag <<<B, T, 0, stream>>>(Pp, Pt);

    const int RB = 2048;                // grid-stride reduction
    k_loss <<<RB, T, 0, stream>>>(preds, targets, Pp, Pt, partial);
    k_final<<<1, T, 0, stream>>>(partial, RB, out);
}

// Round 10
// 487.226 us; speedup vs baseline: 30.9253x; 1.7837x over previous
//
#include <hip/hip_runtime.h>
#include <math.h>

// Problem geometry (fixed by the reference):
//   preds   : (2, 2, 128, 128, 128) float32
//   targets : (2, 1, 128, 128, 128) int32
//   output  : scalar float32 = mean over (2,128,128,128) of
//             0.5*ce*(1 + 0.5*m_neg + 0.5*m_pos)
#define VOL   (128 * 128 * 128)   // 2,097,152 voxels per volume
#define NB    2                   // batch
#define TOTAL (NB * VOL)          // 4,194,304

#define INVP   0x7FFFFFFFu        // background sentinel in global parent arrays
#define FLAGB  0x80000000u        // "component has an error voxel" bit (root entry)
#define IDXM   0x7FFFFFFFu        // mask off the flag bit
#define LINV   0xFFFFFFFFu        // background sentinel in LDS parent arrays

// ---------------- global union-find (atomicMin-monotone, deterministic) ----
__device__ __forceinline__ unsigned find_root(unsigned* P, unsigned i) {
    while (true) {
        unsigned p = P[i] & IDXM;
        if (p == i) return i;
        unsigned gp = P[p] & IDXM;
        if (gp != p) atomicMin(&P[i], gp);   // path-halving, never raises a ptr
        i = gp;
    }
}

__device__ __forceinline__ void unite(unsigned* P, unsigned a, unsigned b) {
    a = find_root(P, a);
    b = find_root(P, b);
    while (a != b) {
        if (b > a) { unsigned t = a; a = b; b = t; }   // link a (larger) under b
        unsigned old = atomicMin(&P[a], b);
        if (old == a) return;
        a = find_root(P, old & IDXM);
        b = find_root(P, b);
    }
}

// ---------------- LDS union-find (same invariants, tile-local ids) ---------
__device__ __forceinline__ unsigned lfind(unsigned* L, unsigned i) {
    while (true) {
        unsigned p = L[i];
        if (p == i) return i;
        unsigned gp = L[p];
        if (gp != p) atomicMin(&L[i], gp);
        i = gp;
    }
}

__device__ __forceinline__ void lunite(unsigned* L, unsigned a, unsigned b) {
    a = lfind(L, a);
    b = lfind(L, b);
    while (a != b) {
        if (b > a) { unsigned t = a; a = b; b = t; }
        unsigned old = atomicMin(&L[a], b);
        if (old == a) return;
        a = lfind(L, old);
        b = lfind(L, b);
    }
}

// Flag the root of g's component, with wave-level dedup + test-before-set
// (R1 measured 14 ms of serialized same-address atomicOr without this).
__device__ __forceinline__ void flag_root_dedup(unsigned* P, bool need, unsigned r) {
    int lane = threadIdx.x & 63;
    unsigned long long rem = __ballot(need);
    while (rem) {
        int src = __ffsll(rem) - 1;
        unsigned rr = __shfl(r, src);
        if (need && r == rr) {
            if (lane == src) {
                if (!(P[rr] & FLAGB)) atomicOr(&P[rr], FLAGB);
            }
            need = false;
        }
        rem = __ballot(need);
    }
}

// ---------------- kernels ----------------

// Phase 1: fused init + tile-local CCL. One block = one 8x8x8 tile (512 vox).
// All intra-tile connectivity resolved via LDS union-find; each voxel's global
// parent is written as the global id of its tile-local root (plain store —
// tile owns these entries exclusively in this kernel).
__global__ void k_local(const float* __restrict__ preds,
                        const int* __restrict__ tgt,
                        unsigned* __restrict__ Pp,
                        unsigned* __restrict__ Pt) {
    __shared__ unsigned lpp[512], lpt[512];
    unsigned tile = blockIdx.x;                  // 0..8191
    unsigned b  = tile >> 12;                    // 4096 tiles per volume
    unsigned tz = (tile >> 8) & 15, ty = (tile >> 4) & 15, tx = tile & 15;
    unsigned base_v = tz * (8 * 16384) + ty * (8 * 128) + tx * 8;  // in-volume
    unsigned base_g = b * VOL + base_v;

    // init: load masks, seed LDS parents
    for (int l = threadIdx.x; l < 512; l += 256) {
        unsigned lx = l & 7, ly = (l >> 3) & 7, lz = l >> 6;
        unsigned voli = base_v + lz * 16384 + ly * 128 + lx;
        float p1 = preds[(size_t)(b * 2 + 1) * VOL + voli];   // channel-1 logit
        int   t  = tgt[b * VOL + voli];
        lpp[l] = (p1 > 0.0f) ? (unsigned)l : LINV;
        lpt[l] = (t > 0)     ? (unsigned)l : LINV;
    }
    __syncthreads();

    // local unites over the 3 forward links (bg entries never participate:
    // fg-ness of an entry is stable — fg stays < 512, bg stays LINV)
    for (int l = threadIdx.x; l < 512; l += 256) {
        unsigned lx = l & 7, ly = (l >> 3) & 7, lz = l >> 6;
        if (lpp[l] != LINV) {
            if (lx < 7 && lpp[l + 1]  != LINV) lunite(lpp, l, l + 1);
            if (ly < 7 && lpp[l + 8]  != LINV) lunite(lpp, l, l + 8);
            if (lz < 7 && lpp[l + 64] != LINV) lunite(lpp, l, l + 64);
        }
        if (lpt[l] != LINV) {
            if (lx < 7 && lpt[l + 1]  != LINV) lunite(lpt, l, l + 1);
            if (ly < 7 && lpt[l + 8]  != LINV) lunite(lpt, l, l + 8);
            if (lz < 7 && lpt[l + 64] != LINV) lunite(lpt, l, l + 64);
        }
    }
    __syncthreads();

    // compress to tile root, write global parents (flat 1-hop trees)
    for (int l = threadIdx.x; l < 512; l += 256) {
        unsigned lx = l & 7, ly = (l >> 3) & 7, lz = l >> 6;
        unsigned g = base_g + lz * 16384 + ly * 128 + lx;
        if (lpp[l] != LINV) {
            unsigned r = lfind(lpp, l);
            Pp[g] = base_g + (r >> 6) * 16384 + ((r >> 3) & 7) * 128 + (r & 7);
        } else Pp[g] = INVP;
        if (lpt[l] != LINV) {
            unsigned r = lfind(lpt, l);
            Pt[g] = base_g + (r >> 6) * 16384 + ((r >> 3) & 7) * 128 + (r & 7);
        } else Pt[g] = INVP;
    }
}

// Phase 2: global unites only across tile faces (~1/8 of links survive).
__global__ void k_bmerge(unsigned* __restrict__ Pp, unsigned* __restrict__ Pt) {
    unsigned g = blockIdx.x * blockDim.x + threadIdx.x;
    if (g >= TOTAL) return;
    unsigned x = g & 127;
    unsigned y = (g >> 7) & 127;
    unsigned z = (g >> 14) & 127;            // z<127 also keeps us inside batch
    bool fx = (x & 7) == 7 && x < 127;       // +x link crosses a tile boundary
    bool fy = (y & 7) == 7 && y < 127;
    bool fz = (z & 7) == 7 && z < 127;
    if (!(fx | fy | fz)) return;
    if (Pp[g] != INVP) {
        if (fx && Pp[g + 1]     != INVP) unite(Pp, g, g + 1);
        if (fy && Pp[g + 128]   != INVP) unite(Pp, g, g + 128);
        if (fz && Pp[g + 16384] != INVP) unite(Pp, g, g + 16384);
    }
    if (Pt[g] != INVP) {
        if (fx && Pt[g + 1]     != INVP) unite(Pt, g, g + 1);
        if (fy && Pt[g + 128]   != INVP) unite(Pt, g, g + 128);
        if (fz && Pt[g + 16384] != INVP) unite(Pt, g, g + 16384);
    }
}

// Compress every fg voxel to its root; set FLAG on the root when the voxel is
// an error w.r.t. the other segmentation. Flags live only on root entries.
__global__ void k_flag(unsigned* __restrict__ Pp, unsigned* __restrict__ Pt) {
    unsigned g = blockIdx.x * blockDim.x + threadIdx.x;
    if (g >= TOTAL) return;
    unsigned vp = Pp[g], vt = Pt[g];
    bool pf = (vp != INVP), tf = (vt != INVP);

    unsigned rp = 0, rt = 0;
    if (pf) {
        rp = find_root(Pp, g);
        if (rp != g) atomicMin(&Pp[g], rp);        // direct link for final pass
    }
    if (tf) {
        rt = find_root(Pt, g);
        if (rt != g) atomicMin(&Pt[g], rt);
    }
    flag_root_dedup(Pp, pf && !tf, rp);   // m_pos: pred comp not covered by tgt
    flag_root_dedup(Pt, tf && !pf, rt);   // m_neg: tgt comp not covered by pred
}

__global__ void k_loss(const float* __restrict__ preds,
                       const int* __restrict__ tgt,
                       const unsigned* __restrict__ Pp,
                       const unsigned* __restrict__ Pt,
                       float* __restrict__ partial) {
    float acc = 0.0f;
    for (unsigned g = blockIdx.x * blockDim.x + threadIdx.x; g < TOTAL;
         g += gridDim.x * blockDim.x) {
        unsigned b = g >> 21;
        unsigned i = g & (VOL - 1);
        float p0 = preds[((size_t)(b * 2 + 0)) * VOL + i];
        float p1 = preds[((size_t)(b * 2 + 1)) * VOL + i];
        int   t  = tgt[g];
        // 2-class CE: -log_softmax(preds)[t] == softplus(p_other - p_t)
        float z  = (t > 0) ? (p0 - p1) : (p1 - p0);
        float ce = (z > 0.0f) ? (z + log1pf(expf(-z))) : log1pf(expf(z));

        unsigned vp = Pp[g], vt = Pt[g];
        float crit = 0.0f;
        if (vt != INVP) {
            unsigned r = vt & IDXM;
            if (Pt[r] & FLAGB) crit += 0.5f;     // BETA * m_neg
        }
        if (vp != INVP) {
            unsigned r = vp & IDXM;
            if (Pp[r] & FLAGB) crit += 0.5f;     // (1-BETA) * m_pos
        }
        acc += 0.5f * ce * (1.0f + crit);        // (1-A)*ce + A*crit*ce, A=0.5
    }
    for (int off = 32; off > 0; off >>= 1) acc += __shfl_down(acc, off);
    __shared__ float s[4];
    int wid = threadIdx.x >> 6, lane = threadIdx.x & 63;
    if (lane == 0) s[wid] = acc;
    __syncthreads();
    if (threadIdx.x == 0) {
        float tacc = 0.0f;
        for (int w = 0; w < (int)(blockDim.x >> 6); ++w) tacc += s[w];
        partial[blockIdx.x] = tacc;
    }
}

__global__ void k_final(const float* __restrict__ partial, int n,
                        float* __restrict__ out) {
    double acc = 0.0;
    for (int i = threadIdx.x; i < n; i += blockDim.x) acc += (double)partial[i];
    for (int off = 32; off > 0; off >>= 1) acc += __shfl_down(acc, off);
    __shared__ double s[4];
    int wid = threadIdx.x >> 6, lane = threadIdx.x & 63;
    if (lane == 0) s[wid] = acc;
    __syncthreads();
    if (threadIdx.x == 0) {
        double t = 0.0;
        for (int w = 0; w < (int)(blockDim.x >> 6); ++w) t += s[w];
        out[0] = (float)(t / (double)TOTAL);
    }
}

// ---------------- launch ----------------

extern "C" void kernel_launch(void* const* d_in, const int* in_sizes, int n_in,
                              void* d_out, int out_size, void* d_ws, size_t ws_size,
                              hipStream_t stream) {
    const float* preds   = (const float*)d_in[0];   // (2,2,128,128,128) f32
    const int*   targets = (const int*)d_in[1];     // (2,1,128,128,128) i32
    float*       out     = (float*)d_out;           // scalar

    // workspace layout: Pp[TOTAL] u32 | Pt[TOTAL] u32 | partial[2048] f32
    unsigned* Pp = (unsigned*)d_ws;
    unsigned* Pt = Pp + TOTAL;
    float* partial = (float*)(Pt + TOTAL);

    const int T = 256;
    const int NTILE = NB * 16 * 16 * 16;      // 8192 8x8x8 tiles
    k_local <<<NTILE, T, 0, stream>>>(preds, targets, Pp, Pt);
    k_bmerge<<<TOTAL / T, T, 0, stream>>>(Pp, Pt);
    k_flag  <<<TOTAL / T, T, 0, stream>>>(Pp, Pt);

    const int RB = 2048;
    k_loss <<<RB, T, 0, stream>>>(preds, targets, Pp, Pt, partial);
    k_final<<<1, T, 0, stream>>>(partial, RB, out);
}

// Round 11
// 374.833 us; speedup vs baseline: 40.1982x; 1.2998x over previous
//
#include <hip/hip_runtime.h>
#include <math.h>

// Problem geometry (fixed by the reference):
//   preds   : (2, 2, 128, 128, 128) float32
//   targets : (2, 1, 128, 128, 128) int32
//   output  : scalar float32 = mean over (2,128,128,128) of
//             0.5*ce*(1 + 0.5*m_neg + 0.5*m_pos)
#define VOL   (128 * 128 * 128)   // 2,097,152 voxels per volume
#define NB    2                   // batch
#define TOTAL (NB * VOL)          // 4,194,304

#define INVP   0x7FFFFFFFu        // background sentinel in global parent arrays
#define FLAGB  0x80000000u        // "component has an error voxel" bit (root entry)
#define IDXM   0x7FFFFFFFu        // mask off the flag bit
#define LINV   0xFFFFFFFFu        // background sentinel in LDS parent arrays

// faces between 8x8x8 tiles: per volume 3 dirs x 15x16x16; two volumes
#define FACES_PER_DIR  (15 * 16 * 16)          // 3840
#define FACES_PER_VOL  (3 * FACES_PER_DIR)     // 11520
#define NFACES         (NB * FACES_PER_VOL)    // 23040

// ---------------- global union-find (atomicMin-monotone, deterministic) ----
__device__ __forceinline__ unsigned find_root(unsigned* P, unsigned i) {
    while (true) {
        unsigned p = P[i] & IDXM;
        if (p == i) return i;
        unsigned gp = P[p] & IDXM;
        if (gp != p) atomicMin(&P[i], gp);   // path-halving, never raises a ptr
        i = gp;
    }
}

__device__ __forceinline__ void unite(unsigned* P, unsigned a, unsigned b) {
    a = find_root(P, a);
    b = find_root(P, b);
    while (a != b) {
        if (b > a) { unsigned t = a; a = b; b = t; }   // link a (larger) under b
        unsigned old = atomicMin(&P[a], b);
        if (old == a) return;
        a = find_root(P, old & IDXM);
        b = find_root(P, b);
    }
}

// ---------------- LDS union-find (same invariants, tile-local ids) ---------
__device__ __forceinline__ unsigned lfind(unsigned* L, unsigned i) {
    while (true) {
        unsigned p = L[i];
        if (p == i) return i;
        unsigned gp = L[p];
        if (gp != p) atomicMin(&L[i], gp);
        i = gp;
    }
}

__device__ __forceinline__ void lunite(unsigned* L, unsigned a, unsigned b) {
    a = lfind(L, a);
    b = lfind(L, b);
    while (a != b) {
        if (b > a) { unsigned t = a; a = b; b = t; }
        unsigned old = atomicMin(&L[a], b);
        if (old == a) return;
        a = lfind(L, old);
        b = lfind(L, b);
    }
}

// Flag the root of g's component, with wave-level dedup + test-before-set
// (R1 measured 14 ms of serialized same-address atomicOr without this).
__device__ __forceinline__ void flag_root_dedup(unsigned* P, bool need, unsigned r) {
    int lane = threadIdx.x & 63;
    unsigned long long rem = __ballot(need);
    while (rem) {
        int src = __ffsll(rem) - 1;
        unsigned rr = __shfl(r, src);
        if (need && r == rr) {
            if (lane == src) {
                if (!(P[rr] & FLAGB)) atomicOr(&P[rr], FLAGB);
            }
            need = false;
        }
        rem = __ballot(need);
    }
}

// ---------------- kernels ----------------

// Phase 1: fused init + tile-local CCL. One block = one 8x8x8 tile (512 vox).
// All intra-tile connectivity resolved via LDS union-find; each voxel's global
// parent is written as the global id of its tile-local root (plain store —
// tile owns these entries exclusively in this kernel).
__global__ void k_local(const float* __restrict__ preds,
                        const int* __restrict__ tgt,
                        unsigned* __restrict__ Pp,
                        unsigned* __restrict__ Pt) {
    __shared__ unsigned lpp[512], lpt[512];
    unsigned tile = blockIdx.x;                  // 0..8191
    unsigned b  = tile >> 12;                    // 4096 tiles per volume
    unsigned tz = (tile >> 8) & 15, ty = (tile >> 4) & 15, tx = tile & 15;
    unsigned base_v = tz * (8 * 16384) + ty * (8 * 128) + tx * 8;  // in-volume
    unsigned base_g = b * VOL + base_v;

    // init: load masks, seed LDS parents
    for (int l = threadIdx.x; l < 512; l += 256) {
        unsigned lx = l & 7, ly = (l >> 3) & 7, lz = l >> 6;
        unsigned voli = base_v + lz * 16384 + ly * 128 + lx;
        float p1 = preds[(size_t)(b * 2 + 1) * VOL + voli];   // channel-1 logit
        int   t  = tgt[b * VOL + voli];
        lpp[l] = (p1 > 0.0f) ? (unsigned)l : LINV;
        lpt[l] = (t > 0)     ? (unsigned)l : LINV;
    }
    __syncthreads();

    // local unites over the 3 forward links (bg entries never participate:
    // fg-ness of an entry is stable — fg stays < 512, bg stays LINV)
    for (int l = threadIdx.x; l < 512; l += 256) {
        unsigned lx = l & 7, ly = (l >> 3) & 7, lz = l >> 6;
        if (lpp[l] != LINV) {
            if (lx < 7 && lpp[l + 1]  != LINV) lunite(lpp, l, l + 1);
            if (ly < 7 && lpp[l + 8]  != LINV) lunite(lpp, l, l + 8);
            if (lz < 7 && lpp[l + 64] != LINV) lunite(lpp, l, l + 64);
        }
        if (lpt[l] != LINV) {
            if (lx < 7 && lpt[l + 1]  != LINV) lunite(lpt, l, l + 1);
            if (ly < 7 && lpt[l + 8]  != LINV) lunite(lpt, l, l + 8);
            if (lz < 7 && lpt[l + 64] != LINV) lunite(lpt, l, l + 64);
        }
    }
    __syncthreads();

    // compress to tile root, write global parents (flat 1-hop trees)
    for (int l = threadIdx.x; l < 512; l += 256) {
        unsigned lx = l & 7, ly = (l >> 3) & 7, lz = l >> 6;
        unsigned g = base_g + lz * 16384 + ly * 128 + lx;
        if (lpp[l] != LINV) {
            unsigned r = lfind(lpp, l);
            Pp[g] = base_g + (r >> 6) * 16384 + ((r >> 3) & 7) * 128 + (r & 7);
        } else Pp[g] = INVP;
        if (lpt[l] != LINV) {
            unsigned r = lfind(lpt, l);
            Pt[g] = base_g + (r >> 6) * 16384 + ((r >> 3) & 7) * 128 + (r & 7);
        } else Pt[g] = INVP;
    }
}

// Phase 2: face-centric boundary merge. One WAVE per tile face (8x8 = 64
// links, one lane each). Stored parents are exact tile roots (k_local wrote
// compressed), so deduping (leftParent, rightParent) pairs within the wave
// is GLOBAL dedup (a tile pair shares exactly one face). One leader lane per
// distinct pair; all leaders unite concurrently (vectorized, not serialized).
__global__ void k_bmerge(unsigned* __restrict__ Pp, unsigned* __restrict__ Pt) {
    unsigned lane = threadIdx.x & 63;
    unsigned fid = blockIdx.x * 4 + (threadIdx.x >> 6);   // 4 waves / block
    if (fid >= NFACES) return;                            // whole wave exits

    unsigned vol = fid / FACES_PER_VOL;
    unsigned r   = fid % FACES_PER_VOL;
    unsigned dir = r / FACES_PER_DIR;
    unsigned fr  = r % FACES_PER_DIR;
    unsigned b0 = fr % 15;            // boundary index along dir (tile b0|b0+1)
    unsigned t1 = (fr / 15) % 16;     // tile coords in the other two axes
    unsigned t2 = fr / 240;
    unsigned u = lane & 7, v = lane >> 3;   // position on the 8x8 face

    unsigned x, y, z, step;
    if (dir == 0)      { x = b0 * 8 + 7; y = t1 * 8 + u; z = t2 * 8 + v; step = 1; }
    else if (dir == 1) { y = b0 * 8 + 7; x = t1 * 8 + u; z = t2 * 8 + v; step = 128; }
    else               { z = b0 * 8 + 7; x = t1 * 8 + u; y = t2 * 8 + v; step = 16384; }
    unsigned g = vol * VOL + z * 16384 + y * 128 + x;

    for (int arr = 0; arr < 2; ++arr) {
        unsigned* P = arr ? Pt : Pp;
        unsigned a = P[g];                 // tile root (or INVP)
        unsigned bb = P[g + step];
        bool need = (a != INVP) && (bb != INVP);
        bool leader = false;
        // peel distinct (a,bb) pairs; mark one leader per pair (no mem ops)
        unsigned long long rem = __ballot(need);
        while (rem) {
            int src = __ffsll(rem) - 1;
            unsigned sa = __shfl(a, src), sb = __shfl(bb, src);
            if (need && a == sa && bb == sb) {
                leader = ((int)lane == src);
                need = false;
            }
            rem = __ballot(need);
        }
        // distinct-pair leaders run their unites together (vector lanes)
        if (leader) unite(P, a, bb);
    }
}

// Compress every fg voxel to its root; set FLAG on the root when the voxel is
// an error w.r.t. the other segmentation. Flags live only on root entries.
__global__ void k_flag(unsigned* __restrict__ Pp, unsigned* __restrict__ Pt) {
    unsigned g = blockIdx.x * blockDim.x + threadIdx.x;
    if (g >= TOTAL) return;
    unsigned vp = Pp[g], vt = Pt[g];
    bool pf = (vp != INVP), tf = (vt != INVP);

    unsigned rp = 0, rt = 0;
    if (pf) {
        rp = find_root(Pp, g);
        if (rp != g) atomicMin(&Pp[g], rp);        // direct link for final pass
    }
    if (tf) {
        rt = find_root(Pt, g);
        if (rt != g) atomicMin(&Pt[g], rt);
    }
    flag_root_dedup(Pp, pf && !tf, rp);   // m_pos: pred comp not covered by tgt
    flag_root_dedup(Pt, tf && !pf, rt);   // m_neg: tgt comp not covered by pred
}

__global__ void k_loss(const float* __restrict__ preds,
                       const int* __restrict__ tgt,
                       const unsigned* __restrict__ Pp,
                       const unsigned* __restrict__ Pt,
                       float* __restrict__ partial) {
    float acc = 0.0f;
    for (unsigned g = blockIdx.x * blockDim.x + threadIdx.x; g < TOTAL;
         g += gridDim.x * blockDim.x) {
        unsigned b = g >> 21;
        unsigned i = g & (VOL - 1);
        float p0 = preds[((size_t)(b * 2 + 0)) * VOL + i];
        float p1 = preds[((size_t)(b * 2 + 1)) * VOL + i];
        int   t  = tgt[g];
        // 2-class CE: -log_softmax(preds)[t] == softplus(p_other - p_t)
        float z  = (t > 0) ? (p0 - p1) : (p1 - p0);
        float ce = (z > 0.0f) ? (z + log1pf(expf(-z))) : log1pf(expf(z));

        unsigned vp = Pp[g], vt = Pt[g];
        float crit = 0.0f;
        if (vt != INVP) {
            unsigned r = vt & IDXM;
            if (Pt[r] & FLAGB) crit += 0.5f;     // BETA * m_neg
        }
        if (vp != INVP) {
            unsigned r = vp & IDXM;
            if (Pp[r] & FLAGB) crit += 0.5f;     // (1-BETA) * m_pos
        }
        acc += 0.5f * ce * (1.0f + crit);        // (1-A)*ce + A*crit*ce, A=0.5
    }
    for (int off = 32; off > 0; off >>= 1) acc += __shfl_down(acc, off);
    __shared__ float s[4];
    int wid = threadIdx.x >> 6, lane = threadIdx.x & 63;
    if (lane == 0) s[wid] = acc;
    __syncthreads();
    if (threadIdx.x == 0) {
        float tacc = 0.0f;
        for (int w = 0; w < (int)(blockDim.x >> 6); ++w) tacc += s[w];
        partial[blockIdx.x] = tacc;
    }
}

__global__ void k_final(const float* __restrict__ partial, int n,
                        float* __restrict__ out) {
    double acc = 0.0;
    for (int i = threadIdx.x; i < n; i += blockDim.x) acc += (double)partial[i];
    for (int off = 32; off > 0; off >>= 1) acc += __shfl_down(acc, off);
    __shared__ double s[4];
    int wid = threadIdx.x >> 6, lane = threadIdx.x & 63;
    if (lane == 0) s[wid] = acc;
    __syncthreads();
    if (threadIdx.x == 0) {
        double t = 0.0;
        for (int w = 0; w < (int)(blockDim.x >> 6); ++w) t += s[w];
        out[0] = (float)(t / (double)TOTAL);
    }
}

// ---------------- launch ----------------

extern "C" void kernel_launch(void* const* d_in, const int* in_sizes, int n_in,
                              void* d_out, int out_size, void* d_ws, size_t ws_size,
                              hipStream_t stream) {
    const float* preds   = (const float*)d_in[0];   // (2,2,128,128,128) f32
    const int*   targets = (const int*)d_in[1];     // (2,1,128,128,128) i32
    float*       out     = (float*)d_out;           // scalar

    // workspace layout: Pp[TOTAL] u32 | Pt[TOTAL] u32 | partial[2048] f32
    unsigned* Pp = (unsigned*)d_ws;
    unsigned* Pt = Pp + TOTAL;
    float* partial = (float*)(Pt + TOTAL);

    const int T = 256;
    const int NTILE = NB * 16 * 16 * 16;      // 8192 8x8x8 tiles
    k_local <<<NTILE, T, 0, stream>>>(preds, targets, Pp, Pt);
    k_bmerge<<<(NFACES + 3) / 4, T, 0, stream>>>(Pp, Pt);   // 1 wave per face
    k_flag  <<<TOTAL / T, T, 0, stream>>>(Pp, Pt);

    const int RB = 2048;
    k_loss <<<RB, T, 0, stream>>>(preds, targets, Pp, Pt, partial);
    k_final<<<1, T, 0, stream>>>(partial, RB, out);
}

// Round 12
// 331.660 us; speedup vs baseline: 45.4310x; 1.1302x over previous
//
#include <hip/hip_runtime.h>
#include <math.h>

// Problem geometry (fixed by the reference):
//   preds   : (2, 2, 128, 128, 128) float32
//   targets : (2, 1, 128, 128, 128) int32
//   output  : scalar float32 = mean over (2,128,128,128) of
//             0.5*ce*(1 + 0.5*m_neg + 0.5*m_pos)
#define VOL   (128 * 128 * 128)   // 2,097,152 voxels per volume
#define NB    2                   // batch
#define TOTAL (NB * VOL)          // 4,194,304

#define INVP   0x7FFFFFFFu        // background sentinel in global parent arrays
#define FLAGB  0x80000000u        // "component has an error voxel" bit (root entry)
#define IDXM   0x7FFFFFFFu        // mask off the flag bit
#define LINV   0xFFFFFFFFu        // background sentinel in LDS parent arrays

// 16x16x16 tiles: 8x8x8 tiles per volume. Faces between tiles:
// per volume 3 dirs x 7x8x8 = 1344; two volumes.
#define TILE_E         16
#define TPV            (8 * 8 * 8)             // tiles per volume: 512
#define FACES_PER_DIR  (7 * 8 * 8)             // 448
#define FACES_PER_VOL  (3 * FACES_PER_DIR)     // 1344
#define NFACES         (NB * FACES_PER_VOL)    // 2688

// ---------------- global union-find (atomicMin-monotone, deterministic) ----
__device__ __forceinline__ unsigned find_root(unsigned* P, unsigned i) {
    while (true) {
        unsigned p = P[i] & IDXM;
        if (p == i) return i;
        unsigned gp = P[p] & IDXM;
        if (gp != p) atomicMin(&P[i], gp);   // path-halving, never raises a ptr
        i = gp;
    }
}

__device__ __forceinline__ void unite(unsigned* P, unsigned a, unsigned b) {
    a = find_root(P, a);
    b = find_root(P, b);
    while (a != b) {
        if (b > a) { unsigned t = a; a = b; b = t; }   // link a (larger) under b
        unsigned old = atomicMin(&P[a], b);
        if (old == a) return;
        a = find_root(P, old & IDXM);
        b = find_root(P, b);
    }
}

// ---------------- LDS union-find (same invariants, tile-local ids) ---------
__device__ __forceinline__ unsigned lfind(unsigned* L, unsigned i) {
    while (true) {
        unsigned p = L[i];
        if (p == i) return i;
        unsigned gp = L[p];
        if (gp != p) atomicMin(&L[i], gp);
        i = gp;
    }
}

__device__ __forceinline__ void lunite(unsigned* L, unsigned a, unsigned b) {
    a = lfind(L, a);
    b = lfind(L, b);
    while (a != b) {
        if (b > a) { unsigned t = a; a = b; b = t; }
        unsigned old = atomicMin(&L[a], b);
        if (old == a) return;
        a = lfind(L, old);
        b = lfind(L, b);
    }
}

// Flag the root of g's component, with wave-level dedup + test-before-set
// (R1 measured 14 ms of serialized same-address atomicOr without this).
__device__ __forceinline__ void flag_root_dedup(unsigned* P, bool need, unsigned r) {
    int lane = threadIdx.x & 63;
    unsigned long long rem = __ballot(need);
    while (rem) {
        int src = __ffsll(rem) - 1;
        unsigned rr = __shfl(r, src);
        if (need && r == rr) {
            if (lane == src) {
                if (!(P[rr] & FLAGB)) atomicOr(&P[rr], FLAGB);
            }
            need = false;
        }
        rem = __ballot(need);
    }
}

// ---------------- kernels ----------------

// Phase 1: fused init + tile-local CCL. One block = one 16x16x16 tile (4096
// voxels, 256 threads x 16). All intra-tile connectivity resolved via LDS
// union-find (32 KB); each voxel's global parent is written as the global id
// of its tile-local root (plain store — tile owns these entries here).
__global__ void k_local(const float* __restrict__ preds,
                        const int* __restrict__ tgt,
                        unsigned* __restrict__ Pp,
                        unsigned* __restrict__ Pt) {
    __shared__ unsigned lpp[4096], lpt[4096];
    unsigned tile = blockIdx.x;                  // 0..1023
    unsigned b  = tile >> 9;                     // 512 tiles per volume
    unsigned tz = (tile >> 6) & 7, ty = (tile >> 3) & 7, tx = tile & 7;
    unsigned base_v = tz * (16 * 16384) + ty * (16 * 128) + tx * 16;
    unsigned base_g = b * VOL + base_v;

    // init: load masks, seed LDS parents
    for (int l = threadIdx.x; l < 4096; l += 256) {
        unsigned lx = l & 15, ly = (l >> 4) & 15, lz = l >> 8;
        unsigned voli = base_v + lz * 16384 + ly * 128 + lx;
        float p1 = preds[(size_t)(b * 2 + 1) * VOL + voli];   // channel-1 logit
        int   t  = tgt[b * VOL + voli];
        lpp[l] = (p1 > 0.0f) ? (unsigned)l : LINV;
        lpt[l] = (t > 0)     ? (unsigned)l : LINV;
    }
    __syncthreads();

    // local unites over the 3 forward links (bg entries never participate:
    // fg-ness of an entry is stable — fg stays < 4096, bg stays LINV)
    for (int l = threadIdx.x; l < 4096; l += 256) {
        unsigned lx = l & 15, ly = (l >> 4) & 15, lz = l >> 8;
        if (lpp[l] != LINV) {
            if (lx < 15 && lpp[l + 1]   != LINV) lunite(lpp, l, l + 1);
            if (ly < 15 && lpp[l + 16]  != LINV) lunite(lpp, l, l + 16);
            if (lz < 15 && lpp[l + 256] != LINV) lunite(lpp, l, l + 256);
        }
        if (lpt[l] != LINV) {
            if (lx < 15 && lpt[l + 1]   != LINV) lunite(lpt, l, l + 1);
            if (ly < 15 && lpt[l + 16]  != LINV) lunite(lpt, l, l + 16);
            if (lz < 15 && lpt[l + 256] != LINV) lunite(lpt, l, l + 256);
        }
    }
    __syncthreads();

    // compress to tile root, write global parents (flat 1-hop trees)
    for (int l = threadIdx.x; l < 4096; l += 256) {
        unsigned lx = l & 15, ly = (l >> 4) & 15, lz = l >> 8;
        unsigned g = base_g + lz * 16384 + ly * 128 + lx;
        if (lpp[l] != LINV) {
            unsigned r = lfind(lpp, l);
            Pp[g] = base_g + (r >> 8) * 16384 + ((r >> 4) & 15) * 128 + (r & 15);
        } else Pp[g] = INVP;
        if (lpt[l] != LINV) {
            unsigned r = lfind(lpt, l);
            Pt[g] = base_g + (r >> 8) * 16384 + ((r >> 4) & 15) * 128 + (r & 15);
        } else Pt[g] = INVP;
    }
}

// Phase 2: face-centric boundary merge. One BLOCK per 16x16 tile face (256
// links, one lane each; 4 waves). Stored parents are exact tile roots, so
// per-wave dedup of (leftParent, rightParent) pairs removes nearly all
// redundant unites (a tile pair shares exactly one face). Leaders of
// distinct pairs unite concurrently as vector lanes.
__global__ void k_bmerge(unsigned* __restrict__ Pp, unsigned* __restrict__ Pt) {
    unsigned fid = blockIdx.x;
    unsigned vol = fid / FACES_PER_VOL;
    unsigned r   = fid % FACES_PER_VOL;
    unsigned dir = r / FACES_PER_DIR;
    unsigned fr  = r % FACES_PER_DIR;
    unsigned b0 = fr % 7;             // boundary index along dir (tile b0|b0+1)
    unsigned t1 = (fr / 7) % 8;       // tile coords in the other two axes
    unsigned t2 = fr / 56;
    unsigned u = threadIdx.x & 15, v = threadIdx.x >> 4;  // 16x16 face pos
    unsigned lane = threadIdx.x & 63;

    unsigned x, y, z, step;
    if (dir == 0)      { x = b0 * 16 + 15; y = t1 * 16 + u; z = t2 * 16 + v; step = 1; }
    else if (dir == 1) { y = b0 * 16 + 15; x = t1 * 16 + u; z = t2 * 16 + v; step = 128; }
    else               { z = b0 * 16 + 15; x = t1 * 16 + u; y = t2 * 16 + v; step = 16384; }
    unsigned g = vol * VOL + z * 16384 + y * 128 + x;

    for (int arr = 0; arr < 2; ++arr) {
        unsigned* P = arr ? Pt : Pp;
        unsigned a = P[g];                 // tile root (or INVP)
        unsigned bb = P[g + step];
        bool need = (a != INVP) && (bb != INVP);
        bool leader = false;
        // peel distinct (a,bb) pairs within the wave; one leader per pair
        unsigned long long rem = __ballot(need);
        while (rem) {
            int src = __ffsll(rem) - 1;
            unsigned sa = __shfl(a, src), sb = __shfl(bb, src);
            if (need && a == sa && bb == sb) {
                leader = ((int)lane == src);
                need = false;
            }
            rem = __ballot(need);
        }
        // distinct-pair leaders run their unites together (vector lanes)
        if (leader) unite(P, a, bb);
    }
}

// Compress every fg voxel to its root; set FLAG on the root when the voxel is
// an error w.r.t. the other segmentation. Flags live only on root entries.
__global__ void k_flag(unsigned* __restrict__ Pp, unsigned* __restrict__ Pt) {
    unsigned g = blockIdx.x * blockDim.x + threadIdx.x;
    if (g >= TOTAL) return;
    unsigned vp = Pp[g], vt = Pt[g];
    bool pf = (vp != INVP), tf = (vt != INVP);

    unsigned rp = 0, rt = 0;
    if (pf) {
        rp = find_root(Pp, g);
        if (rp != g) atomicMin(&Pp[g], rp);        // direct link for final pass
    }
    if (tf) {
        rt = find_root(Pt, g);
        if (rt != g) atomicMin(&Pt[g], rt);
    }
    flag_root_dedup(Pp, pf && !tf, rp);   // m_pos: pred comp not covered by tgt
    flag_root_dedup(Pt, tf && !pf, rt);   // m_neg: tgt comp not covered by pred
}

__global__ void k_loss(const float* __restrict__ preds,
                       const int* __restrict__ tgt,
                       const unsigned* __restrict__ Pp,
                       const unsigned* __restrict__ Pt,
                       float* __restrict__ partial) {
    float acc = 0.0f;
    for (unsigned g = blockIdx.x * blockDim.x + threadIdx.x; g < TOTAL;
         g += gridDim.x * blockDim.x) {
        unsigned b = g >> 21;
        unsigned i = g & (VOL - 1);
        float p0 = preds[((size_t)(b * 2 + 0)) * VOL + i];
        float p1 = preds[((size_t)(b * 2 + 1)) * VOL + i];
        int   t  = tgt[g];
        // 2-class CE: -log_softmax(preds)[t] == softplus(p_other - p_t)
        float z  = (t > 0) ? (p0 - p1) : (p1 - p0);
        float ce = (z > 0.0f) ? (z + log1pf(expf(-z))) : log1pf(expf(z));

        unsigned vp = Pp[g], vt = Pt[g];
        float crit = 0.0f;
        if (vt != INVP) {
            unsigned r = vt & IDXM;
            if (Pt[r] & FLAGB) crit += 0.5f;     // BETA * m_neg
        }
        if (vp != INVP) {
            unsigned r = vp & IDXM;
            if (Pp[r] & FLAGB) crit += 0.5f;     // (1-BETA) * m_pos
        }
        acc += 0.5f * ce * (1.0f + crit);        // (1-A)*ce + A*crit*ce, A=0.5
    }
    for (int off = 32; off > 0; off >>= 1) acc += __shfl_down(acc, off);
    __shared__ float s[4];
    int wid = threadIdx.x >> 6, lane = threadIdx.x & 63;
    if (lane == 0) s[wid] = acc;
    __syncthreads();
    if (threadIdx.x == 0) {
        float tacc = 0.0f;
        for (int w = 0; w < (int)(blockDim.x >> 6); ++w) tacc += s[w];
        partial[blockIdx.x] = tacc;
    }
}

__global__ void k_final(const float* __restrict__ partial, int n,
                        float* __restrict__ out) {
    double acc = 0.0;
    for (int i = threadIdx.x; i < n; i += blockDim.x) acc += (double)partial[i];
    for (int off = 32; off > 0; off >>= 1) acc += __shfl_down(acc, off);
    __shared__ double s[4];
    int wid = threadIdx.x >> 6, lane = threadIdx.x & 63;
    if (lane == 0) s[wid] = acc;
    __syncthreads();
    if (threadIdx.x == 0) {
        double t = 0.0;
        for (int w = 0; w < (int)(blockDim.x >> 6); ++w) t += s[w];
        out[0] = (float)(t / (double)TOTAL);
    }
}

// ---------------- launch ----------------

extern "C" void kernel_launch(void* const* d_in, const int* in_sizes, int n_in,
                              void* d_out, int out_size, void* d_ws, size_t ws_size,
                              hipStream_t stream) {
    const float* preds   = (const float*)d_in[0];   // (2,2,128,128,128) f32
    const int*   targets = (const int*)d_in[1];     // (2,1,128,128,128) i32
    float*       out     = (float*)d_out;           // scalar

    // workspace layout: Pp[TOTAL] u32 | Pt[TOTAL] u32 | partial[2048] f32
    unsigned* Pp = (unsigned*)d_ws;
    unsigned* Pt = Pp + TOTAL;
    float* partial = (float*)(Pt + TOTAL);

    const int T = 256;
    const int NTILE = NB * TPV;               // 1024 16x16x16 tiles
    k_local <<<NTILE, T, 0, stream>>>(preds, targets, Pp, Pt);
    k_bmerge<<<NFACES, T, 0, stream>>>(Pp, Pt);   // 1 block per 16x16 face
    k_flag  <<<TOTAL / T, T, 0, stream>>>(Pp, Pt);

    const int RB = 2048;
    k_loss <<<RB, T, 0, stream>>>(preds, targets, Pp, Pt, partial);
    k_final<<<1, T, 0, stream>>>(partial, RB, out);
}